// Round 5
// baseline (2089.649 us; speedup 1.0000x reference)
//
#include <hip/hip_runtime.h>
#include <hip/hip_fp16.h>

// ---------------------------------------------------------------------------
// Decagon GCN forward, round 7.
// R6 -> R7: reorder4 was the top kernel (~260us) with WRITE_SIZE 251MB for a
// 32MB payload: 4M random 8B stores, one 64B HBM line each (cross-XCD line
// bounce defeats L2/L3 write coalescing). Replaced by a binned two-phase
// scatter:
//   scatter_bins: pos = cursor-atomic (unchanged); append 12B record
//     (pos,col,val) to bin pos/1680 via per-bin atomic counter. Positions are
//     unique so bin fill <= BINW; ~4k hot bin tails stay in L3 and fill lines
//     completely -> dense writes (~50MB).
//   place_bins: one WG per bin; scatter records into spair. Write window per
//     WG = 13.4KB (64B-aligned, single XCD) -> L2-coalesced dense writes.
// Bin buffer time-aliases the g/hw16 scratch (only live during CSR build).
// Everything else identical to R6 (fp16 gather tables etc).
// ---------------------------------------------------------------------------

#define HDIM 64
#define BINW 1680   // positions per bin; 1680*8B = 13440B = 210 cache lines

__device__ inline unsigned pack2h(float a, float b) {
    return (unsigned)__half_as_ushort(__float2half_rn(a)) |
           ((unsigned)__half_as_ushort(__float2half_rn(b)) << 16);
}

// ---- layer-1 GEMM: hw16_t[N,64] = feat_{t&1}[N,128] @ W1_t[128,64], t=blockIdx.y
__global__ __launch_bounds__(256) void gemm_l1(const float* __restrict__ in0,
                                               const float* __restrict__ in1,
                                               const float* __restrict__ Wall,
                                               __half* __restrict__ hw16, int N) {
    const int K = 128;
    __shared__ __align__(16) float Ws[128 * 64];
    __shared__ __align__(16) float As[16 * 68];

    const int t = blockIdx.y;
    const float* A = (t & 1) ? in1 : in0;
    const float* W = Wall + (size_t)t * K * HDIM;
    __half*      C = hw16 + (size_t)t * (size_t)N * HDIM;

    const int tid  = threadIdx.x;
    const int row0 = blockIdx.x * 64;

    for (int off = tid * 4; off < K * 64; off += 1024)
        *(float4*)(Ws + off) = *(const float4*)(W + off);

    const int tx = tid & 15;
    const int ty = tid >> 4;
    const int lr = tid >> 2;
    const int kq = tid & 3;

    float acc[4][4];
#pragma unroll
    for (int i = 0; i < 4; i++)
#pragma unroll
        for (int j = 0; j < 4; j++) acc[i][j] = 0.f;

    const int grow = row0 + lr;
    const float* Arow = A + (size_t)grow * K;

    for (int k0 = 0; k0 < K; k0 += 16) {
        __syncthreads();
        float4 av = make_float4(0.f, 0.f, 0.f, 0.f);
        if (grow < N) av = *(const float4*)(Arow + k0 + kq * 4);
        As[(kq * 4 + 0) * 68 + lr] = av.x;
        As[(kq * 4 + 1) * 68 + lr] = av.y;
        As[(kq * 4 + 2) * 68 + lr] = av.z;
        As[(kq * 4 + 3) * 68 + lr] = av.w;
        __syncthreads();

#pragma unroll
        for (int kk = 0; kk < 16; kk++) {
            float4 a4 = *(const float4*)(As + kk * 68 + ty * 4);
            float4 b4 = *(const float4*)(Ws + (k0 + kk) * 64 + tx * 4);
            float avv[4] = {a4.x, a4.y, a4.z, a4.w};
            float bvv[4] = {b4.x, b4.y, b4.z, b4.w};
#pragma unroll
            for (int i = 0; i < 4; i++)
#pragma unroll
                for (int j = 0; j < 4; j++)
                    acc[i][j] = fmaf(avv[i], bvv[j], acc[i][j]);
        }
    }

#pragma unroll
    for (int i = 0; i < 4; i++) {
        int r = row0 + ty * 4 + i;
        if (r < N) {
            uint2 pk;
            pk.x = pack2h(acc[i][0], acc[i][1]);
            pk.y = pack2h(acc[i][2], acc[i][3]);
            *(uint2*)(C + (size_t)r * HDIM + tx * 4) = pk;
        }
    }
}

// ---- layers 2-5 GEMM: C_h[N,64] = g_h[N,128] @ Wstack_h[128,64], h=blockIdx.y
// MODE 0: fp16 pre-act only (e2,e3).  MODE 1: fp16 + fp32 pre-act (e1).
// MODE 2: FIN epilogue  out = concat(relu(h1)*a0, relu(e1)*a1, (p+relu(h1))*a2)
template <int MODE>
__global__ __launch_bounds__(256) void gemm_h2(const float* __restrict__ g,
                                               const float* __restrict__ Wl,
                                               __half* __restrict__ o16,
                                               float* __restrict__ o32,
                                               const float* __restrict__ h1,
                                               const float* __restrict__ e1,
                                               const float* __restrict__ att,
                                               float* __restrict__ outF, int N) {
    const int K = 128;
    __shared__ __align__(16) float Ws[128 * 64];
    __shared__ __align__(16) float As[16 * 68];

    const int t = blockIdx.y;
    const size_t NH = (size_t)N * HDIM;
    const float* A = g + (size_t)t * (size_t)N * K;
    const float* W = Wl + (size_t)t * 8192;   // [W_{2t}; W_{2t+1}] contiguous

    const int tid  = threadIdx.x;
    const int row0 = blockIdx.x * 64;

    for (int off = tid * 4; off < K * 64; off += 1024)
        *(float4*)(Ws + off) = *(const float4*)(W + off);

    const int tx = tid & 15;
    const int ty = tid >> 4;
    const int lr = tid >> 2;
    const int kq = tid & 3;

    float acc[4][4];
#pragma unroll
    for (int i = 0; i < 4; i++)
#pragma unroll
        for (int j = 0; j < 4; j++) acc[i][j] = 0.f;

    const int grow = row0 + lr;
    const float* Arow = A + (size_t)grow * K;

    for (int k0 = 0; k0 < K; k0 += 16) {
        __syncthreads();
        float4 av = make_float4(0.f, 0.f, 0.f, 0.f);
        if (grow < N) av = *(const float4*)(Arow + k0 + kq * 4);
        As[(kq * 4 + 0) * 68 + lr] = av.x;
        As[(kq * 4 + 1) * 68 + lr] = av.y;
        As[(kq * 4 + 2) * 68 + lr] = av.z;
        As[(kq * 4 + 3) * 68 + lr] = av.w;
        __syncthreads();

#pragma unroll
        for (int kk = 0; kk < 16; kk++) {
            float4 a4 = *(const float4*)(As + kk * 68 + ty * 4);
            float4 b4 = *(const float4*)(Ws + (k0 + kk) * 64 + tx * 4);
            float avv[4] = {a4.x, a4.y, a4.z, a4.w};
            float bvv[4] = {b4.x, b4.y, b4.z, b4.w};
#pragma unroll
            for (int i = 0; i < 4; i++)
#pragma unroll
                for (int j = 0; j < 4; j++)
                    acc[i][j] = fmaf(avv[i], bvv[j], acc[i][j]);
        }
    }

    if (MODE != 2) {
#pragma unroll
        for (int i = 0; i < 4; i++) {
            int r = row0 + ty * 4 + i;
            if (r < N) {
                size_t idx = (size_t)t * NH + (size_t)r * HDIM + tx * 4;
                uint2 pk;
                pk.x = pack2h(acc[i][0], acc[i][1]);
                pk.y = pack2h(acc[i][2], acc[i][3]);
                *(uint2*)(o16 + idx) = pk;
                if (MODE == 1) {
                    float4 o = make_float4(acc[i][0], acc[i][1], acc[i][2], acc[i][3]);
                    *(float4*)(o32 + idx) = o;
                }
            }
        }
    } else {
        const float a0 = att[0], a1 = att[1], a2 = att[2];
#pragma unroll
        for (int i = 0; i < 4; i++) {
            int r = row0 + ty * 4 + i;
            if (r < N) {
                size_t idx = (size_t)t * NH + (size_t)r * HDIM + tx * 4;
                float4 h4 = *(const float4*)(h1 + idx);
                float4 e4 = *(const float4*)(e1 + idx);
                float hh[4] = {fmaxf(h4.x, 0.f), fmaxf(h4.y, 0.f),
                               fmaxf(h4.z, 0.f), fmaxf(h4.w, 0.f)};
                float ee[4] = {fmaxf(e4.x, 0.f), fmaxf(e4.y, 0.f),
                               fmaxf(e4.z, 0.f), fmaxf(e4.w, 0.f)};
                size_t base = (size_t)t * (size_t)N * 192 + (size_t)r * 192 + tx * 4;
                *(float4*)(outF + base) =
                    make_float4(hh[0] * a0, hh[1] * a0, hh[2] * a0, hh[3] * a0);
                *(float4*)(outF + base + 64) =
                    make_float4(ee[0] * a1, ee[1] * a1, ee[2] * a1, ee[3] * a1);
                *(float4*)(outF + base + 128) =
                    make_float4((acc[i][0] + hh[0]) * a2, (acc[i][1] + hh[1]) * a2,
                                (acc[i][2] + hh[2]) * a2, (acc[i][3] + hh[3]) * a2);
            }
        }
    }
}

// --- CSR build (padded-to-8 segments, interleaved (col,val) pairs) ---------

__global__ __launch_bounds__(256) void hist4(const int* __restrict__ rows,
                                             int* __restrict__ cnt, int E, int N) {
    int e = blockIdx.x * 256 + threadIdx.x;
    int t = blockIdx.y;
    if (e < E) atomicAdd(&cnt[t * N + rows[(size_t)t * E + e]], 1);
}

__global__ __launch_bounds__(256) void scan_sums(const int* __restrict__ cnt,
                                                 int* __restrict__ partials, int M) {
    __shared__ int red[256];
    int base = blockIdx.x * 1024 + threadIdx.x * 4;
    int s = 0;
#pragma unroll
    for (int j = 0; j < 4; j++) {
        int i = base + j;
        if (i < M) s += (cnt[i] + 7) & ~7;
    }
    red[threadIdx.x] = s;
    __syncthreads();
    for (int off = 128; off > 0; off >>= 1) {
        if (threadIdx.x < off) red[threadIdx.x] += red[threadIdx.x + off];
        __syncthreads();
    }
    if (threadIdx.x == 0) partials[blockIdx.x] = red[0];
}

__global__ __launch_bounds__(1024) void scan_partials(int* __restrict__ partials, int B) {
    __shared__ int buf[1024];
    int t = threadIdx.x;
    int v = (t < B) ? partials[t] : 0;
    buf[t] = v;
    __syncthreads();
    for (int off = 1; off < 1024; off <<= 1) {
        int add = (t >= off) ? buf[t - off] : 0;
        __syncthreads();
        buf[t] += add;
        __syncthreads();
    }
    if (t < B) partials[t] = buf[t] - v;  // exclusive
}

__global__ __launch_bounds__(256) void scan_final(int* __restrict__ cnt,
                                                  const int* __restrict__ partials,
                                                  int* __restrict__ start, int M) {
    __shared__ int red[256];
    int tid = threadIdx.x;
    int base = blockIdx.x * 1024 + tid * 4;
    int v[4];
    int s = 0;
#pragma unroll
    for (int j = 0; j < 4; j++) {
        int i = base + j;
        v[j] = (i < M) ? ((cnt[i] + 7) & ~7) : 0;
        s += v[j];
    }
    red[tid] = s;
    __syncthreads();
    int mine = s;
    for (int off = 1; off < 256; off <<= 1) {
        int add = (tid >= off) ? red[tid - off] : 0;
        __syncthreads();
        red[tid] += add;
        __syncthreads();
    }
    int excl = red[tid] - mine + partials[blockIdx.x];
#pragma unroll
    for (int j = 0; j < 4; j++) {
        int i = base + j;
        if (i < M) {
            start[i] = excl;
            cnt[i]   = excl;          // scatter cursor starts at segment base
            excl += v[j];
            if (i == M - 1) start[M] = excl;
        }
    }
}

// Phase A: pos via cursor atomic; append (pos,col,val) 12B record to bin
// pos/BINW at a per-bin tail counter. Bin tails are ~4k hot lines in L3 ->
// lines fill completely before eviction -> dense HBM writes.
__global__ __launch_bounds__(256) void scatter_bins(const int* __restrict__ rows,
                                                    const int* __restrict__ cols,
                                                    const float* __restrict__ vals,
                                                    int* __restrict__ cursor,
                                                    int* __restrict__ bincnt,
                                                    unsigned* __restrict__ binbuf,
                                                    int E, int N) {
    int e = blockIdx.x * 256 + threadIdx.x;
    int t = blockIdx.y;
    if (e >= E) return;
    size_t o = (size_t)t * E + e;
    int pos = atomicAdd(&cursor[t * N + rows[o]], 1);
    int b   = pos / BINW;                       // magic-mul divide
    int idx = atomicAdd(&bincnt[b], 1);         // idx < BINW (positions unique)
    size_t rb = ((size_t)b * BINW + idx) * 3;
    binbuf[rb]     = (unsigned)pos;
    binbuf[rb + 1] = (unsigned)cols[o];
    binbuf[rb + 2] = __float_as_uint(vals[o]);
}

// Phase B: one WG per bin; scatter records into spair. Write window per WG =
// BINW*8B = 13.4KB (64B-aligned, single XCD) -> L2 coalesces -> dense writes.
__global__ __launch_bounds__(256) void place_bins(const int* __restrict__ bincnt,
                                                  const unsigned* __restrict__ binbuf,
                                                  int2* __restrict__ spair) {
    int b = blockIdx.x;
    int n = bincnt[b];
    const unsigned* rec = binbuf + (size_t)b * BINW * 3;
    for (int i = threadIdx.x; i < n; i += 256) {
        unsigned pos = rec[3 * i];
        spair[pos] = make_int2((int)rec[3 * i + 1], (int)rec[3 * i + 2]);
    }
}

// --- gathers (fp16 tables) -------------------------------------------------

// layer 1 (gather-after): h1_h[row] = sum_{t=2h,2h+1} adj_t-row . hw16_t
__global__ __launch_bounds__(256) void gatherA(const __half* __restrict__ hw16,
                                               const int* __restrict__ start,
                                               const int4* __restrict__ sp4,
                                               float* __restrict__ h32,
                                               __half* __restrict__ h16, int N) {
    const int half = blockIdx.y;
    const int row  = blockIdx.x * 4 + (threadIdx.x >> 6);
    const int lane = threadIdx.x & 63;
    if (row >= N) return;
    const size_t NH = (size_t)N * HDIM;
    float accA = 0.f, accB = 0.f;

#pragma unroll
    for (int p = 0; p < 2; p++) {
        const int tt = half * 2 + p;
        const __half* __restrict__ h = hw16 + (size_t)tt * NH;
        int beg = __builtin_amdgcn_readfirstlane(start[tt * N + row]);
        int end = __builtin_amdgcn_readfirstlane(start[tt * N + row + 1]);
        for (int e = beg; e < end; e += 8) {
            int c[8]; float v[8];
#pragma unroll
            for (int u = 0; u < 4; u++) {
                int4 q = sp4[(e >> 1) + u];
                c[2 * u]     = q.x; v[2 * u]     = __int_as_float(q.y);
                c[2 * u + 1] = q.z; v[2 * u + 1] = __int_as_float(q.w);
            }
            float hv[8];
#pragma unroll
            for (int u = 0; u < 8; u++)
                hv[u] = __half2float(h[(size_t)c[u] * HDIM + lane]);
#pragma unroll
            for (int u = 0; u < 8; u += 2) {
                accA = fmaf(v[u],     hv[u],     accA);
                accB = fmaf(v[u + 1], hv[u + 1], accB);
            }
        }
    }
    float r = accA + accB;
    size_t idx = (size_t)half * NH + (size_t)row * HDIM + lane;
    h32[idx] = r;
    h16[idx] = __float2half_rn(r);
}

// layers 2-5 (gather-first): g_h[row][p*64+lane] = adj_{2h+p}-row . relu(in16_{p})
__global__ __launch_bounds__(256) void gatherF(const __half* __restrict__ in16,
                                               const int* __restrict__ start,
                                               const int4* __restrict__ sp4,
                                               float* __restrict__ g, int N) {
    const int half = blockIdx.y;
    const int row  = blockIdx.x * 4 + (threadIdx.x >> 6);
    const int lane = threadIdx.x & 63;
    if (row >= N) return;
    const size_t NH = (size_t)N * HDIM;
    float* gout = g + ((size_t)half * N + row) * 128 + lane;

#pragma unroll
    for (int p = 0; p < 2; p++) {
        const int tt = half * 2 + p;
        const __half* __restrict__ h = in16 + (size_t)(tt & 1) * NH;
        int beg = __builtin_amdgcn_readfirstlane(start[tt * N + row]);
        int end = __builtin_amdgcn_readfirstlane(start[tt * N + row + 1]);
        float accA = 0.f, accB = 0.f;
        for (int e = beg; e < end; e += 8) {
            int c[8]; float v[8];
#pragma unroll
            for (int u = 0; u < 4; u++) {
                int4 q = sp4[(e >> 1) + u];
                c[2 * u]     = q.x; v[2 * u]     = __int_as_float(q.y);
                c[2 * u + 1] = q.z; v[2 * u + 1] = __int_as_float(q.w);
            }
            float hv[8];
#pragma unroll
            for (int u = 0; u < 8; u++)
                hv[u] = fmaxf(__half2float(h[(size_t)c[u] * HDIM + lane]), 0.f);
#pragma unroll
            for (int u = 0; u < 8; u += 2) {
                accA = fmaf(v[u],     hv[u],     accA);
                accB = fmaf(v[u + 1], hv[u + 1], accB);
            }
        }
        gout[p * 64] = accA + accB;
    }
}

extern "C" void kernel_launch(void* const* d_in, const int* in_sizes, int n_in,
                              void* d_out, int out_size, void* d_ws, size_t ws_size,
                              hipStream_t stream) {
    const float* feat0 = (const float*)d_in[0];
    const float* feat1 = (const float*)d_in[1];
    const int*   rows  = (const int*)d_in[2];
    const int*   cols  = (const int*)d_in[3];
    const float* vals  = (const float*)d_in[4];
    const float* W1    = (const float*)d_in[5];
    const float* W2    = (const float*)d_in[6];
    const float* W3    = (const float*)d_in[7];
    const float* W4    = (const float*)d_in[8];
    const float* W5    = (const float*)d_in[9];
    const float* att   = (const float*)d_in[10];

    const int N = in_sizes[0] / 128;   // 100000
    const int E = in_sizes[2] / 4;     // 1000000
    const size_t NH = (size_t)N * HDIM;
    const int M = 4 * N;
    const int PadCap = 4 * E + 7 * M;  // max padded CSR entries
    const int NBINS  = (PadCap + BINW - 1) / BINW;

    float* ws  = (float*)d_ws;
    float* h10 = ws + 0 * NH;            // h1 fp32 [2NH] (epilogue residual)
    float* e10 = ws + 2 * NH;            // e1 fp32 [2NH] (epilogue)
    float* g   = ws + 4 * NH;            // [2][N][128] fp32; aliases hw16 + binbuf
    __half* hw16 = (__half*)g;           // [4][N][64] fp16 (layer-1 only)
    unsigned* binbuf = (unsigned*)g;     // NBINS*BINW*3 u32 (CSR build only, ~82MB)
    __half* f16  = (__half*)(ws + 8 * NH);
    __half* h16  = f16 + 0 * 2 * NH;     // [2][N][64] fp16 each
    __half* e16  = f16 + 1 * 2 * NH;
    __half* a16  = f16 + 2 * 2 * NH;
    __half* b16  = f16 + 3 * 2 * NH;     // f16 region = 8NH halves = 4NH floats

    int2*  spair    = (int2*)(ws + 12 * NH);       // PadCap pairs (16B-aligned)
    int*   start    = (int*)(spair + PadCap);      // M+1
    int*   cursor   = start + (M + 1);             // M
    int*   partials = cursor + M;                  // <=1024
    int*   bincnt   = partials + 1024;             // NBINS

    const int gblk = (N + 63) / 64;
    const int eblk = (E + 255) / 256;
    const int B    = (M + 1023) / 1024;
    const int gr2  = (N + 3) / 4;

    // ---- CSR build (once; graph reused by all 5 layers) ----
    hipMemsetAsync(cursor, 0, (size_t)M * sizeof(int), stream);
    hipMemsetAsync(bincnt, 0, (size_t)NBINS * sizeof(int), stream);
    hipMemsetAsync(spair, 0, (size_t)PadCap * sizeof(int2), stream);  // pads -> (0,0)
    hist4<<<dim3(eblk, 4), 256, 0, stream>>>(rows, cursor, E, N);
    scan_sums<<<B, 256, 0, stream>>>(cursor, partials, M);
    scan_partials<<<1, 1024, 0, stream>>>(partials, B);
    scan_final<<<B, 256, 0, stream>>>(cursor, partials, start, M);
    scatter_bins<<<dim3(eblk, 4), 256, 0, stream>>>(rows, cols, vals, cursor,
                                                    bincnt, binbuf, E, N);
    place_bins<<<NBINS, 256, 0, stream>>>(bincnt, binbuf, spair);

    const int4* sp4 = (const int4*)spair;

    // ---- layer 1: GEMM-first (feat is 128-wide), gather-after ----
    gemm_l1<<<dim3(gblk, 4), 256, 0, stream>>>(feat0, feat1, W1, hw16, N);
    gatherA<<<dim3(gr2, 2), 256, 0, stream>>>(hw16, start, sp4, h10, h16, N);

    // ---- layer 2: gather-first, GEMM stores fp32+fp16 (e1 feeds epilogue) ----
    gatherF<<<dim3(gr2, 2), 256, 0, stream>>>(h16, start, sp4, g, N);
    gemm_h2<1><<<dim3(gblk, 2), 256, 0, stream>>>(g, W2, e16, e10,
                                                  nullptr, nullptr, nullptr, nullptr, N);

    // ---- layers 3-4: gather-first, fp16-only pre-act ----
    gatherF<<<dim3(gr2, 2), 256, 0, stream>>>(e16, start, sp4, g, N);
    gemm_h2<0><<<dim3(gblk, 2), 256, 0, stream>>>(g, W3, a16, nullptr,
                                                  nullptr, nullptr, nullptr, nullptr, N);
    gatherF<<<dim3(gr2, 2), 256, 0, stream>>>(a16, start, sp4, g, N);
    gemm_h2<0><<<dim3(gblk, 2), 256, 0, stream>>>(g, W4, b16, nullptr,
                                                  nullptr, nullptr, nullptr, nullptr, N);

    // ---- layer 5: gather-first + GEMM with fused attention/concat epilogue ----
    gatherF<<<dim3(gr2, 2), 256, 0, stream>>>(b16, start, sp4, g, N);
    gemm_h2<2><<<dim3(gblk, 2), 256, 0, stream>>>(g, W5, nullptr, nullptr,
                                                  h10, e10, att, (float*)d_out, N);
}

// Round 6
// 1483.506 us; speedup vs baseline: 1.4086x; 1.4086x over previous
//
#include <hip/hip_runtime.h>
#include <hip/hip_fp16.h>

// ---------------------------------------------------------------------------
// Decagon GCN forward, round 8.
// R7 post-mortem: binned scatter REGRESSED (790us, WRITE 336MB). Lesson:
// cross-XCD partial-line writes always cost a full line (non-coherent L2s
// write back per-owner); temporal tail locality doesn't coalesce. Only
// single-XCD spatial contiguity does.
// R8: CSR scatter rebuilt on that invariant, zero global atomics:
//   split_pass: 64 WGs (16 stripes x 4 types); each appends 8B records
//     (row_local||col, val) into PRIVATE per-(stripe,bucket) regions
//     (782 buckets of 128 rows/type, cap 160 = mean 80 + 9sigma). Per-WG
//     footprint 1MB -> lives in its own XCD L2 -> dense writebacks.
//     LDS cursors only.
//   place_pass: one WG per (type,bucket): read 16 stripe-regions (dense),
//     final padded positions via LDS per-row cursors seeded from start[],
//     build span in LDS (pads zeroed), write span densely. Also removes
//     the 54MB memset(spair).
// Everything else identical to R6 (fp16 gather tables, fused GEMMs).
// ---------------------------------------------------------------------------

#define HDIM 64
#define STRIPES 16     // edge stripes per type
#define BROWS   128    // rows per bucket
#define RCAP    160    // record capacity per (stripe,bucket); mean 80 + 9sigma
#define SPANCAP 3072   // LDS span entries per bucket; max ~2360

__device__ inline unsigned pack2h(float a, float b) {
    return (unsigned)__half_as_ushort(__float2half_rn(a)) |
           ((unsigned)__half_as_ushort(__float2half_rn(b)) << 16);
}

// ---- layer-1 GEMM: hw16_t[N,64] = feat_{t&1}[N,128] @ W1_t[128,64], t=blockIdx.y
__global__ __launch_bounds__(256) void gemm_l1(const float* __restrict__ in0,
                                               const float* __restrict__ in1,
                                               const float* __restrict__ Wall,
                                               __half* __restrict__ hw16, int N) {
    const int K = 128;
    __shared__ __align__(16) float Ws[128 * 64];
    __shared__ __align__(16) float As[16 * 68];

    const int t = blockIdx.y;
    const float* A = (t & 1) ? in1 : in0;
    const float* W = Wall + (size_t)t * K * HDIM;
    __half*      C = hw16 + (size_t)t * (size_t)N * HDIM;

    const int tid  = threadIdx.x;
    const int row0 = blockIdx.x * 64;

    for (int off = tid * 4; off < K * 64; off += 1024)
        *(float4*)(Ws + off) = *(const float4*)(W + off);

    const int tx = tid & 15;
    const int ty = tid >> 4;
    const int lr = tid >> 2;
    const int kq = tid & 3;

    float acc[4][4];
#pragma unroll
    for (int i = 0; i < 4; i++)
#pragma unroll
        for (int j = 0; j < 4; j++) acc[i][j] = 0.f;

    const int grow = row0 + lr;
    const float* Arow = A + (size_t)grow * K;

    for (int k0 = 0; k0 < K; k0 += 16) {
        __syncthreads();
        float4 av = make_float4(0.f, 0.f, 0.f, 0.f);
        if (grow < N) av = *(const float4*)(Arow + k0 + kq * 4);
        As[(kq * 4 + 0) * 68 + lr] = av.x;
        As[(kq * 4 + 1) * 68 + lr] = av.y;
        As[(kq * 4 + 2) * 68 + lr] = av.z;
        As[(kq * 4 + 3) * 68 + lr] = av.w;
        __syncthreads();

#pragma unroll
        for (int kk = 0; kk < 16; kk++) {
            float4 a4 = *(const float4*)(As + kk * 68 + ty * 4);
            float4 b4 = *(const float4*)(Ws + (k0 + kk) * 64 + tx * 4);
            float avv[4] = {a4.x, a4.y, a4.z, a4.w};
            float bvv[4] = {b4.x, b4.y, b4.z, b4.w};
#pragma unroll
            for (int i = 0; i < 4; i++)
#pragma unroll
                for (int j = 0; j < 4; j++)
                    acc[i][j] = fmaf(avv[i], bvv[j], acc[i][j]);
        }
    }

#pragma unroll
    for (int i = 0; i < 4; i++) {
        int r = row0 + ty * 4 + i;
        if (r < N) {
            uint2 pk;
            pk.x = pack2h(acc[i][0], acc[i][1]);
            pk.y = pack2h(acc[i][2], acc[i][3]);
            *(uint2*)(C + (size_t)r * HDIM + tx * 4) = pk;
        }
    }
}

// ---- layers 2-5 GEMM: C_h[N,64] = g_h[N,128] @ Wstack_h[128,64], h=blockIdx.y
// MODE 0: fp16 pre-act only (e2,e3).  MODE 1: fp16 + fp32 pre-act (e1).
// MODE 2: FIN epilogue  out = concat(relu(h1)*a0, relu(e1)*a1, (p+relu(h1))*a2)
template <int MODE>
__global__ __launch_bounds__(256) void gemm_h2(const float* __restrict__ g,
                                               const float* __restrict__ Wl,
                                               __half* __restrict__ o16,
                                               float* __restrict__ o32,
                                               const float* __restrict__ h1,
                                               const float* __restrict__ e1,
                                               const float* __restrict__ att,
                                               float* __restrict__ outF, int N) {
    const int K = 128;
    __shared__ __align__(16) float Ws[128 * 64];
    __shared__ __align__(16) float As[16 * 68];

    const int t = blockIdx.y;
    const size_t NH = (size_t)N * HDIM;
    const float* A = g + (size_t)t * (size_t)N * K;
    const float* W = Wl + (size_t)t * 8192;   // [W_{2t}; W_{2t+1}] contiguous

    const int tid  = threadIdx.x;
    const int row0 = blockIdx.x * 64;

    for (int off = tid * 4; off < K * 64; off += 1024)
        *(float4*)(Ws + off) = *(const float4*)(W + off);

    const int tx = tid & 15;
    const int ty = tid >> 4;
    const int lr = tid >> 2;
    const int kq = tid & 3;

    float acc[4][4];
#pragma unroll
    for (int i = 0; i < 4; i++)
#pragma unroll
        for (int j = 0; j < 4; j++) acc[i][j] = 0.f;

    const int grow = row0 + lr;
    const float* Arow = A + (size_t)grow * K;

    for (int k0 = 0; k0 < K; k0 += 16) {
        __syncthreads();
        float4 av = make_float4(0.f, 0.f, 0.f, 0.f);
        if (grow < N) av = *(const float4*)(Arow + k0 + kq * 4);
        As[(kq * 4 + 0) * 68 + lr] = av.x;
        As[(kq * 4 + 1) * 68 + lr] = av.y;
        As[(kq * 4 + 2) * 68 + lr] = av.z;
        As[(kq * 4 + 3) * 68 + lr] = av.w;
        __syncthreads();

#pragma unroll
        for (int kk = 0; kk < 16; kk++) {
            float4 a4 = *(const float4*)(As + kk * 68 + ty * 4);
            float4 b4 = *(const float4*)(Ws + (k0 + kk) * 64 + tx * 4);
            float avv[4] = {a4.x, a4.y, a4.z, a4.w};
            float bvv[4] = {b4.x, b4.y, b4.z, b4.w};
#pragma unroll
            for (int i = 0; i < 4; i++)
#pragma unroll
                for (int j = 0; j < 4; j++)
                    acc[i][j] = fmaf(avv[i], bvv[j], acc[i][j]);
        }
    }

    if (MODE != 2) {
#pragma unroll
        for (int i = 0; i < 4; i++) {
            int r = row0 + ty * 4 + i;
            if (r < N) {
                size_t idx = (size_t)t * NH + (size_t)r * HDIM + tx * 4;
                uint2 pk;
                pk.x = pack2h(acc[i][0], acc[i][1]);
                pk.y = pack2h(acc[i][2], acc[i][3]);
                *(uint2*)(o16 + idx) = pk;
                if (MODE == 1) {
                    float4 o = make_float4(acc[i][0], acc[i][1], acc[i][2], acc[i][3]);
                    *(float4*)(o32 + idx) = o;
                }
            }
        }
    } else {
        const float a0 = att[0], a1 = att[1], a2 = att[2];
#pragma unroll
        for (int i = 0; i < 4; i++) {
            int r = row0 + ty * 4 + i;
            if (r < N) {
                size_t idx = (size_t)t * NH + (size_t)r * HDIM + tx * 4;
                float4 h4 = *(const float4*)(h1 + idx);
                float4 e4 = *(const float4*)(e1 + idx);
                float hh[4] = {fmaxf(h4.x, 0.f), fmaxf(h4.y, 0.f),
                               fmaxf(h4.z, 0.f), fmaxf(h4.w, 0.f)};
                float ee[4] = {fmaxf(e4.x, 0.f), fmaxf(e4.y, 0.f),
                               fmaxf(e4.z, 0.f), fmaxf(e4.w, 0.f)};
                size_t base = (size_t)t * (size_t)N * 192 + (size_t)r * 192 + tx * 4;
                *(float4*)(outF + base) =
                    make_float4(hh[0] * a0, hh[1] * a0, hh[2] * a0, hh[3] * a0);
                *(float4*)(outF + base + 64) =
                    make_float4(ee[0] * a1, ee[1] * a1, ee[2] * a1, ee[3] * a1);
                *(float4*)(outF + base + 128) =
                    make_float4((acc[i][0] + hh[0]) * a2, (acc[i][1] + hh[1]) * a2,
                                (acc[i][2] + hh[2]) * a2, (acc[i][3] + hh[3]) * a2);
            }
        }
    }
}

// --- CSR build -------------------------------------------------------------

__global__ __launch_bounds__(256) void hist4(const int* __restrict__ rows,
                                             int* __restrict__ cnt, int E, int N) {
    int e = blockIdx.x * 256 + threadIdx.x;
    int t = blockIdx.y;
    if (e < E) atomicAdd(&cnt[t * N + rows[(size_t)t * E + e]], 1);
}

__global__ __launch_bounds__(256) void scan_sums(const int* __restrict__ cnt,
                                                 int* __restrict__ partials, int M) {
    __shared__ int red[256];
    int base = blockIdx.x * 1024 + threadIdx.x * 4;
    int s = 0;
#pragma unroll
    for (int j = 0; j < 4; j++) {
        int i = base + j;
        if (i < M) s += (cnt[i] + 7) & ~7;
    }
    red[threadIdx.x] = s;
    __syncthreads();
    for (int off = 128; off > 0; off >>= 1) {
        if (threadIdx.x < off) red[threadIdx.x] += red[threadIdx.x + off];
        __syncthreads();
    }
    if (threadIdx.x == 0) partials[blockIdx.x] = red[0];
}

__global__ __launch_bounds__(1024) void scan_partials(int* __restrict__ partials, int B) {
    __shared__ int buf[1024];
    int t = threadIdx.x;
    int v = (t < B) ? partials[t] : 0;
    buf[t] = v;
    __syncthreads();
    for (int off = 1; off < 1024; off <<= 1) {
        int add = (t >= off) ? buf[t - off] : 0;
        __syncthreads();
        buf[t] += add;
        __syncthreads();
    }
    if (t < B) partials[t] = buf[t] - v;  // exclusive
}

__global__ __launch_bounds__(256) void scan_final(int* __restrict__ cnt,
                                                  const int* __restrict__ partials,
                                                  int* __restrict__ start, int M) {
    __shared__ int red[256];
    int tid = threadIdx.x;
    int base = blockIdx.x * 1024 + tid * 4;
    int v[4];
    int s = 0;
#pragma unroll
    for (int j = 0; j < 4; j++) {
        int i = base + j;
        v[j] = (i < M) ? ((cnt[i] + 7) & ~7) : 0;
        s += v[j];
    }
    red[tid] = s;
    __syncthreads();
    int mine = s;
    for (int off = 1; off < 256; off <<= 1) {
        int add = (tid >= off) ? red[tid - off] : 0;
        __syncthreads();
        red[tid] += add;
        __syncthreads();
    }
    int excl = red[tid] - mine + partials[blockIdx.x];
#pragma unroll
    for (int j = 0; j < 4; j++) {
        int i = base + j;
        if (i < M) {
            start[i] = excl;
            excl += v[j];
            if (i == M - 1) start[M] = excl;
        }
    }
}

// Pass A: stripe (blockIdx.x) x type (blockIdx.y). Append (row_local||col,val)
// into PRIVATE per-(stripe,bucket) regions via LDS cursors — no global
// atomics. Per-WG write window ~1MB -> single-XCD L2 -> dense writebacks.
__global__ __launch_bounds__(256) void split_pass(const int* __restrict__ rows,
                                                  const int* __restrict__ cols,
                                                  const float* __restrict__ vals,
                                                  int2* __restrict__ rbuf,
                                                  int* __restrict__ cnt_sb,
                                                  int E, int nbt) {
    __shared__ int cur[1024];           // nbt <= 1024
    const int s = blockIdx.x;
    const int t = blockIdx.y;
    for (int i = threadIdx.x; i < nbt; i += 256) cur[i] = 0;
    __syncthreads();

    const int es = (E + STRIPES - 1) / STRIPES;
    const int e0 = s * es;
    const int e1 = min(e0 + es, E);
    const size_t base = (size_t)t * E;
    int2* rb = rbuf + (size_t)(t * STRIPES + s) * nbt * RCAP;

    for (int e = e0 + threadIdx.x; e < e1; e += 256) {
        int r = rows[base + e];
        int b = r >> 7;                 // BROWS = 128
        int idx = atomicAdd(&cur[b], 1);
        if (idx < RCAP) {               // 9-sigma margin; guard vs OOB
            int rl = r & 127;
            rb[(size_t)b * RCAP + idx] =
                make_int2((rl << 17) | cols[base + e], __float_as_int(vals[base + e]));
        }
    }
    __syncthreads();
    for (int i = threadIdx.x; i < nbt; i += 256)
        cnt_sb[(t * STRIPES + s) * nbt + i] = min(cur[i], RCAP);
}

// Pass B: one WG per (type,bucket). Read the 16 stripe-regions (dense),
// place records at final padded positions via LDS per-row cursors seeded
// from start[], then write the whole span densely (pads = zeros).
__global__ __launch_bounds__(256) void place_pass(const int2* __restrict__ rbuf,
                                                  const int* __restrict__ cnt_sb,
                                                  const int* __restrict__ start,
                                                  int2* __restrict__ spair,
                                                  int N, int nbt) {
    __shared__ int  lcur[BROWS];
    __shared__ int2 span[SPANCAP];
    const int b = blockIdx.x;
    const int t = blockIdx.y;
    const int r0 = b * BROWS;
    const int rows_here = min(BROWS, N - r0);
    if (rows_here <= 0) return;
    const int g0 = t * N + r0;
    const int p0 = start[g0];
    const int p1 = start[g0 + rows_here];
    const int spanlen = p1 - p0;        // <= SPANCAP by construction

    for (int i = threadIdx.x; i < spanlen; i += 256) span[i] = make_int2(0, 0);
    for (int i = threadIdx.x; i < rows_here; i += 256) lcur[i] = start[g0 + i] - p0;
    __syncthreads();

    for (int s = 0; s < STRIPES; s++) {
        const int sb = (t * STRIPES + s) * nbt + b;
        const int n = cnt_sb[sb];
        const int2* rec = rbuf + (size_t)sb * RCAP;
        for (int i = threadIdx.x; i < n; i += 256) {
            int2 q = rec[i];
            int rl = ((unsigned)q.x) >> 17;
            int idx = atomicAdd(&lcur[rl], 1);
            if (idx < SPANCAP) span[idx] = make_int2(q.x & 0x1FFFF, q.y);
        }
    }
    __syncthreads();
    int2* out = spair + p0;
    for (int i = threadIdx.x; i < spanlen; i += 256) out[i] = span[i];
}

// --- gathers (fp16 tables) -------------------------------------------------

// layer 1 (gather-after): h1_h[row] = sum_{t=2h,2h+1} adj_t-row . hw16_t
__global__ __launch_bounds__(256) void gatherA(const __half* __restrict__ hw16,
                                               const int* __restrict__ start,
                                               const int4* __restrict__ sp4,
                                               float* __restrict__ h32,
                                               __half* __restrict__ h16, int N) {
    const int half = blockIdx.y;
    const int row  = blockIdx.x * 4 + (threadIdx.x >> 6);
    const int lane = threadIdx.x & 63;
    if (row >= N) return;
    const size_t NH = (size_t)N * HDIM;
    float accA = 0.f, accB = 0.f;

#pragma unroll
    for (int p = 0; p < 2; p++) {
        const int tt = half * 2 + p;
        const __half* __restrict__ h = hw16 + (size_t)tt * NH;
        int beg = __builtin_amdgcn_readfirstlane(start[tt * N + row]);
        int end = __builtin_amdgcn_readfirstlane(start[tt * N + row + 1]);
        for (int e = beg; e < end; e += 8) {
            int c[8]; float v[8];
#pragma unroll
            for (int u = 0; u < 4; u++) {
                int4 q = sp4[(e >> 1) + u];
                c[2 * u]     = q.x; v[2 * u]     = __int_as_float(q.y);
                c[2 * u + 1] = q.z; v[2 * u + 1] = __int_as_float(q.w);
            }
            float hv[8];
#pragma unroll
            for (int u = 0; u < 8; u++)
                hv[u] = __half2float(h[(size_t)c[u] * HDIM + lane]);
#pragma unroll
            for (int u = 0; u < 8; u += 2) {
                accA = fmaf(v[u],     hv[u],     accA);
                accB = fmaf(v[u + 1], hv[u + 1], accB);
            }
        }
    }
    float r = accA + accB;
    size_t idx = (size_t)half * NH + (size_t)row * HDIM + lane;
    h32[idx] = r;
    h16[idx] = __float2half_rn(r);
}

// layers 2-5 (gather-first): g_h[row][p*64+lane] = adj_{2h+p}-row . relu(in16_{p})
__global__ __launch_bounds__(256) void gatherF(const __half* __restrict__ in16,
                                               const int* __restrict__ start,
                                               const int4* __restrict__ sp4,
                                               float* __restrict__ g, int N) {
    const int half = blockIdx.y;
    const int row  = blockIdx.x * 4 + (threadIdx.x >> 6);
    const int lane = threadIdx.x & 63;
    if (row >= N) return;
    const size_t NH = (size_t)N * HDIM;
    float* gout = g + ((size_t)half * N + row) * 128 + lane;

#pragma unroll
    for (int p = 0; p < 2; p++) {
        const int tt = half * 2 + p;
        const __half* __restrict__ h = in16 + (size_t)(tt & 1) * NH;
        int beg = __builtin_amdgcn_readfirstlane(start[tt * N + row]);
        int end = __builtin_amdgcn_readfirstlane(start[tt * N + row + 1]);
        float accA = 0.f, accB = 0.f;
        for (int e = beg; e < end; e += 8) {
            int c[8]; float v[8];
#pragma unroll
            for (int u = 0; u < 4; u++) {
                int4 q = sp4[(e >> 1) + u];
                c[2 * u]     = q.x; v[2 * u]     = __int_as_float(q.y);
                c[2 * u + 1] = q.z; v[2 * u + 1] = __int_as_float(q.w);
            }
            float hv[8];
#pragma unroll
            for (int u = 0; u < 8; u++)
                hv[u] = fmaxf(__half2float(h[(size_t)c[u] * HDIM + lane]), 0.f);
#pragma unroll
            for (int u = 0; u < 8; u += 2) {
                accA = fmaf(v[u],     hv[u],     accA);
                accB = fmaf(v[u + 1], hv[u + 1], accB);
            }
        }
        gout[p * 64] = accA + accB;
    }
}

extern "C" void kernel_launch(void* const* d_in, const int* in_sizes, int n_in,
                              void* d_out, int out_size, void* d_ws, size_t ws_size,
                              hipStream_t stream) {
    const float* feat0 = (const float*)d_in[0];
    const float* feat1 = (const float*)d_in[1];
    const int*   rows  = (const int*)d_in[2];
    const int*   cols  = (const int*)d_in[3];
    const float* vals  = (const float*)d_in[4];
    const float* W1    = (const float*)d_in[5];
    const float* W2    = (const float*)d_in[6];
    const float* W3    = (const float*)d_in[7];
    const float* W4    = (const float*)d_in[8];
    const float* W5    = (const float*)d_in[9];
    const float* att   = (const float*)d_in[10];

    const int N = in_sizes[0] / 128;   // 100000
    const int E = in_sizes[2] / 4;     // 1000000
    const size_t NH = (size_t)N * HDIM;
    const int M = 4 * N;
    const int PadCap = 4 * E + 7 * M;  // max padded CSR entries
    const int nbt = (N + BROWS - 1) / BROWS;   // buckets per type (782)

    float* ws  = (float*)d_ws;
    float* h10 = ws + 0 * NH;            // h1 fp32 [2NH] (epilogue residual)
    float* e10 = ws + 2 * NH;            // e1 fp32 [2NH] (epilogue)
    float* g   = ws + 4 * NH;            // [2][N][128] fp32; aliases hw16 + rbuf
    __half* hw16 = (__half*)g;           // [4][N][64] fp16 (layer-1 only)
    int2*   rbuf = (int2*)g;             // 64*nbt*RCAP records (~64MB, build only)
    __half* f16  = (__half*)(ws + 8 * NH);
    __half* h16  = f16 + 0 * 2 * NH;     // [2][N][64] fp16 each
    __half* e16  = f16 + 1 * 2 * NH;
    __half* a16  = f16 + 2 * 2 * NH;
    __half* b16  = f16 + 3 * 2 * NH;     // f16 region = 8NH halves = 4NH floats

    int2*  spair    = (int2*)(ws + 12 * NH);       // PadCap pairs (16B-aligned)
    int*   start    = (int*)(spair + PadCap);      // M+1
    int*   cursor   = start + (M + 1);             // M (hist counts)
    int*   partials = cursor + M;                  // <=1024
    int*   cnt_sb   = partials + 1024;             // 64*nbt

    const int gblk = (N + 63) / 64;
    const int eblk = (E + 255) / 256;
    const int B    = (M + 1023) / 1024;
    const int gr2  = (N + 3) / 4;

    // ---- CSR build (once; graph reused by all 5 layers) ----
    hipMemsetAsync(cursor, 0, (size_t)M * sizeof(int), stream);
    hist4<<<dim3(eblk, 4), 256, 0, stream>>>(rows, cursor, E, N);
    scan_sums<<<B, 256, 0, stream>>>(cursor, partials, M);
    scan_partials<<<1, 1024, 0, stream>>>(partials, B);
    scan_final<<<B, 256, 0, stream>>>(cursor, partials, start, M);
    split_pass<<<dim3(STRIPES, 4), 256, 0, stream>>>(rows, cols, vals, rbuf, cnt_sb, E, nbt);
    place_pass<<<dim3(nbt, 4), 256, 0, stream>>>(rbuf, cnt_sb, start, spair, N, nbt);

    const int4* sp4 = (const int4*)spair;

    // ---- layer 1: GEMM-first (feat is 128-wide), gather-after ----
    gemm_l1<<<dim3(gblk, 4), 256, 0, stream>>>(feat0, feat1, W1, hw16, N);
    gatherA<<<dim3(gr2, 2), 256, 0, stream>>>(hw16, start, sp4, h10, h16, N);

    // ---- layer 2: gather-first, GEMM stores fp32+fp16 (e1 feeds epilogue) ----
    gatherF<<<dim3(gr2, 2), 256, 0, stream>>>(h16, start, sp4, g, N);
    gemm_h2<1><<<dim3(gblk, 2), 256, 0, stream>>>(g, W2, e16, e10,
                                                  nullptr, nullptr, nullptr, nullptr, N);

    // ---- layers 3-4: gather-first, fp16-only pre-act ----
    gatherF<<<dim3(gr2, 2), 256, 0, stream>>>(e16, start, sp4, g, N);
    gemm_h2<0><<<dim3(gblk, 2), 256, 0, stream>>>(g, W3, a16, nullptr,
                                                  nullptr, nullptr, nullptr, nullptr, N);
    gatherF<<<dim3(gr2, 2), 256, 0, stream>>>(a16, start, sp4, g, N);
    gemm_h2<0><<<dim3(gblk, 2), 256, 0, stream>>>(g, W4, b16, nullptr,
                                                  nullptr, nullptr, nullptr, nullptr, N);

    // ---- layer 5: gather-first + GEMM with fused attention/concat epilogue ----
    gatherF<<<dim3(gr2, 2), 256, 0, stream>>>(b16, start, sp4, g, N);
    gemm_h2<2><<<dim3(gblk, 2), 256, 0, stream>>>(g, W5, nullptr, nullptr,
                                                  h10, e10, att, (float*)d_out, N);
}

// Round 7
// 1376.589 us; speedup vs baseline: 1.5180x; 1.0777x over previous
//
#include <hip/hip_runtime.h>
#include <hip/hip_fp16.h>

// ---------------------------------------------------------------------------
// Decagon GCN forward, round 9.
// R8 post-mortem: split_pass achieved dense writes (WRITE 251->34MB, model
// confirmed) but grid was 64 WGs -> 2.8% occupancy, latency-serialized at
// 206us. R9: scale out, same footprint:
//   split_pass: 64 stripes x 4 types = 256 WGs x 1024 thr (16 waves/CU).
//     RCAP 160->60 (mean 20/bucket, +8.9sigma). rbuf 96.1MB still fits g.
//   place_pass: consume loop flattened over (stripe x slot) so all 256
//     lanes are active (was ~20/256 per stripe read).
// Everything else identical to R8 (fp16 gather tables, fused GEMMs).
// ---------------------------------------------------------------------------

#define HDIM 64
#define STRIPES 64     // edge stripes per type
#define BROWS   128    // rows per bucket
#define RCAP    60     // records per (stripe,bucket); mean 20 + 8.9 sigma
#define SPANCAP 3072   // LDS span entries per bucket; max ~2500

__device__ inline unsigned pack2h(float a, float b) {
    return (unsigned)__half_as_ushort(__float2half_rn(a)) |
           ((unsigned)__half_as_ushort(__float2half_rn(b)) << 16);
}

// ---- layer-1 GEMM: hw16_t[N,64] = feat_{t&1}[N,128] @ W1_t[128,64], t=blockIdx.y
__global__ __launch_bounds__(256) void gemm_l1(const float* __restrict__ in0,
                                               const float* __restrict__ in1,
                                               const float* __restrict__ Wall,
                                               __half* __restrict__ hw16, int N) {
    const int K = 128;
    __shared__ __align__(16) float Ws[128 * 64];
    __shared__ __align__(16) float As[16 * 68];

    const int t = blockIdx.y;
    const float* A = (t & 1) ? in1 : in0;
    const float* W = Wall + (size_t)t * K * HDIM;
    __half*      C = hw16 + (size_t)t * (size_t)N * HDIM;

    const int tid  = threadIdx.x;
    const int row0 = blockIdx.x * 64;

    for (int off = tid * 4; off < K * 64; off += 1024)
        *(float4*)(Ws + off) = *(const float4*)(W + off);

    const int tx = tid & 15;
    const int ty = tid >> 4;
    const int lr = tid >> 2;
    const int kq = tid & 3;

    float acc[4][4];
#pragma unroll
    for (int i = 0; i < 4; i++)
#pragma unroll
        for (int j = 0; j < 4; j++) acc[i][j] = 0.f;

    const int grow = row0 + lr;
    const float* Arow = A + (size_t)grow * K;

    for (int k0 = 0; k0 < K; k0 += 16) {
        __syncthreads();
        float4 av = make_float4(0.f, 0.f, 0.f, 0.f);
        if (grow < N) av = *(const float4*)(Arow + k0 + kq * 4);
        As[(kq * 4 + 0) * 68 + lr] = av.x;
        As[(kq * 4 + 1) * 68 + lr] = av.y;
        As[(kq * 4 + 2) * 68 + lr] = av.z;
        As[(kq * 4 + 3) * 68 + lr] = av.w;
        __syncthreads();

#pragma unroll
        for (int kk = 0; kk < 16; kk++) {
            float4 a4 = *(const float4*)(As + kk * 68 + ty * 4);
            float4 b4 = *(const float4*)(Ws + (k0 + kk) * 64 + tx * 4);
            float avv[4] = {a4.x, a4.y, a4.z, a4.w};
            float bvv[4] = {b4.x, b4.y, b4.z, b4.w};
#pragma unroll
            for (int i = 0; i < 4; i++)
#pragma unroll
                for (int j = 0; j < 4; j++)
                    acc[i][j] = fmaf(avv[i], bvv[j], acc[i][j]);
        }
    }

#pragma unroll
    for (int i = 0; i < 4; i++) {
        int r = row0 + ty * 4 + i;
        if (r < N) {
            uint2 pk;
            pk.x = pack2h(acc[i][0], acc[i][1]);
            pk.y = pack2h(acc[i][2], acc[i][3]);
            *(uint2*)(C + (size_t)r * HDIM + tx * 4) = pk;
        }
    }
}

// ---- layers 2-5 GEMM: C_h[N,64] = g_h[N,128] @ Wstack_h[128,64], h=blockIdx.y
// MODE 0: fp16 pre-act only (e2,e3).  MODE 1: fp16 + fp32 pre-act (e1).
// MODE 2: FIN epilogue  out = concat(relu(h1)*a0, relu(e1)*a1, (p+relu(h1))*a2)
template <int MODE>
__global__ __launch_bounds__(256) void gemm_h2(const float* __restrict__ g,
                                               const float* __restrict__ Wl,
                                               __half* __restrict__ o16,
                                               float* __restrict__ o32,
                                               const float* __restrict__ h1,
                                               const float* __restrict__ e1,
                                               const float* __restrict__ att,
                                               float* __restrict__ outF, int N) {
    const int K = 128;
    __shared__ __align__(16) float Ws[128 * 64];
    __shared__ __align__(16) float As[16 * 68];

    const int t = blockIdx.y;
    const size_t NH = (size_t)N * HDIM;
    const float* A = g + (size_t)t * (size_t)N * K;
    const float* W = Wl + (size_t)t * 8192;   // [W_{2t}; W_{2t+1}] contiguous

    const int tid  = threadIdx.x;
    const int row0 = blockIdx.x * 64;

    for (int off = tid * 4; off < K * 64; off += 1024)
        *(float4*)(Ws + off) = *(const float4*)(W + off);

    const int tx = tid & 15;
    const int ty = tid >> 4;
    const int lr = tid >> 2;
    const int kq = tid & 3;

    float acc[4][4];
#pragma unroll
    for (int i = 0; i < 4; i++)
#pragma unroll
        for (int j = 0; j < 4; j++) acc[i][j] = 0.f;

    const int grow = row0 + lr;
    const float* Arow = A + (size_t)grow * K;

    for (int k0 = 0; k0 < K; k0 += 16) {
        __syncthreads();
        float4 av = make_float4(0.f, 0.f, 0.f, 0.f);
        if (grow < N) av = *(const float4*)(Arow + k0 + kq * 4);
        As[(kq * 4 + 0) * 68 + lr] = av.x;
        As[(kq * 4 + 1) * 68 + lr] = av.y;
        As[(kq * 4 + 2) * 68 + lr] = av.z;
        As[(kq * 4 + 3) * 68 + lr] = av.w;
        __syncthreads();

#pragma unroll
        for (int kk = 0; kk < 16; kk++) {
            float4 a4 = *(const float4*)(As + kk * 68 + ty * 4);
            float4 b4 = *(const float4*)(Ws + (k0 + kk) * 64 + tx * 4);
            float avv[4] = {a4.x, a4.y, a4.z, a4.w};
            float bvv[4] = {b4.x, b4.y, b4.z, b4.w};
#pragma unroll
            for (int i = 0; i < 4; i++)
#pragma unroll
                for (int j = 0; j < 4; j++)
                    acc[i][j] = fmaf(avv[i], bvv[j], acc[i][j]);
        }
    }

    if (MODE != 2) {
#pragma unroll
        for (int i = 0; i < 4; i++) {
            int r = row0 + ty * 4 + i;
            if (r < N) {
                size_t idx = (size_t)t * NH + (size_t)r * HDIM + tx * 4;
                uint2 pk;
                pk.x = pack2h(acc[i][0], acc[i][1]);
                pk.y = pack2h(acc[i][2], acc[i][3]);
                *(uint2*)(o16 + idx) = pk;
                if (MODE == 1) {
                    float4 o = make_float4(acc[i][0], acc[i][1], acc[i][2], acc[i][3]);
                    *(float4*)(o32 + idx) = o;
                }
            }
        }
    } else {
        const float a0 = att[0], a1 = att[1], a2 = att[2];
#pragma unroll
        for (int i = 0; i < 4; i++) {
            int r = row0 + ty * 4 + i;
            if (r < N) {
                size_t idx = (size_t)t * NH + (size_t)r * HDIM + tx * 4;
                float4 h4 = *(const float4*)(h1 + idx);
                float4 e4 = *(const float4*)(e1 + idx);
                float hh[4] = {fmaxf(h4.x, 0.f), fmaxf(h4.y, 0.f),
                               fmaxf(h4.z, 0.f), fmaxf(h4.w, 0.f)};
                float ee[4] = {fmaxf(e4.x, 0.f), fmaxf(e4.y, 0.f),
                               fmaxf(e4.z, 0.f), fmaxf(e4.w, 0.f)};
                size_t base = (size_t)t * (size_t)N * 192 + (size_t)r * 192 + tx * 4;
                *(float4*)(outF + base) =
                    make_float4(hh[0] * a0, hh[1] * a0, hh[2] * a0, hh[3] * a0);
                *(float4*)(outF + base + 64) =
                    make_float4(ee[0] * a1, ee[1] * a1, ee[2] * a1, ee[3] * a1);
                *(float4*)(outF + base + 128) =
                    make_float4((acc[i][0] + hh[0]) * a2, (acc[i][1] + hh[1]) * a2,
                                (acc[i][2] + hh[2]) * a2, (acc[i][3] + hh[3]) * a2);
            }
        }
    }
}

// --- CSR build -------------------------------------------------------------

__global__ __launch_bounds__(256) void hist4(const int* __restrict__ rows,
                                             int* __restrict__ cnt, int E, int N) {
    int e = blockIdx.x * 256 + threadIdx.x;
    int t = blockIdx.y;
    if (e < E) atomicAdd(&cnt[t * N + rows[(size_t)t * E + e]], 1);
}

__global__ __launch_bounds__(256) void scan_sums(const int* __restrict__ cnt,
                                                 int* __restrict__ partials, int M) {
    __shared__ int red[256];
    int base = blockIdx.x * 1024 + threadIdx.x * 4;
    int s = 0;
#pragma unroll
    for (int j = 0; j < 4; j++) {
        int i = base + j;
        if (i < M) s += (cnt[i] + 7) & ~7;
    }
    red[threadIdx.x] = s;
    __syncthreads();
    for (int off = 128; off > 0; off >>= 1) {
        if (threadIdx.x < off) red[threadIdx.x] += red[threadIdx.x + off];
        __syncthreads();
    }
    if (threadIdx.x == 0) partials[blockIdx.x] = red[0];
}

__global__ __launch_bounds__(1024) void scan_partials(int* __restrict__ partials, int B) {
    __shared__ int buf[1024];
    int t = threadIdx.x;
    int v = (t < B) ? partials[t] : 0;
    buf[t] = v;
    __syncthreads();
    for (int off = 1; off < 1024; off <<= 1) {
        int add = (t >= off) ? buf[t - off] : 0;
        __syncthreads();
        buf[t] += add;
        __syncthreads();
    }
    if (t < B) partials[t] = buf[t] - v;  // exclusive
}

__global__ __launch_bounds__(256) void scan_final(int* __restrict__ cnt,
                                                  const int* __restrict__ partials,
                                                  int* __restrict__ start, int M) {
    __shared__ int red[256];
    int tid = threadIdx.x;
    int base = blockIdx.x * 1024 + tid * 4;
    int v[4];
    int s = 0;
#pragma unroll
    for (int j = 0; j < 4; j++) {
        int i = base + j;
        v[j] = (i < M) ? ((cnt[i] + 7) & ~7) : 0;
        s += v[j];
    }
    red[tid] = s;
    __syncthreads();
    int mine = s;
    for (int off = 1; off < 256; off <<= 1) {
        int add = (tid >= off) ? red[tid - off] : 0;
        __syncthreads();
        red[tid] += add;
        __syncthreads();
    }
    int excl = red[tid] - mine + partials[blockIdx.x];
#pragma unroll
    for (int j = 0; j < 4; j++) {
        int i = base + j;
        if (i < M) {
            start[i] = excl;
            excl += v[j];
            if (i == M - 1) start[M] = excl;
        }
    }
}

// Pass A: stripe (blockIdx.x, 64) x type (blockIdx.y, 4) = 256 WGs x 1024 thr.
// Append (row_local||col, val) into PRIVATE per-(stripe,bucket) regions via
// LDS cursors — no global atomics. Hot tail lines ~50KB/WG, 32 WGs/XCD ->
// 1.6MB < 4MB L2: all writers of a line on one XCD -> dense writebacks.
__global__ __launch_bounds__(1024) void split_pass(const int* __restrict__ rows,
                                                   const int* __restrict__ cols,
                                                   const float* __restrict__ vals,
                                                   int2* __restrict__ rbuf,
                                                   int* __restrict__ cnt_sb,
                                                   int E, int nbt) {
    __shared__ int cur[1024];           // nbt <= 1024
    const int s = blockIdx.x;
    const int t = blockIdx.y;
    for (int i = threadIdx.x; i < nbt; i += 1024) cur[i] = 0;
    __syncthreads();

    const int es = (E + STRIPES - 1) / STRIPES;
    const int e0 = s * es;
    const int e1 = min(e0 + es, E);
    const size_t base = (size_t)t * E;
    int2* rb = rbuf + (size_t)(t * STRIPES + s) * nbt * RCAP;

    for (int e = e0 + threadIdx.x; e < e1; e += 1024) {
        int r = rows[base + e];
        int b = r >> 7;                 // BROWS = 128
        int idx = atomicAdd(&cur[b], 1);
        if (idx < RCAP) {               // ~9-sigma margin; guard vs OOB
            int rl = r & 127;
            rb[(size_t)b * RCAP + idx] =
                make_int2((rl << 17) | cols[base + e], __float_as_int(vals[base + e]));
        }
    }
    __syncthreads();
    for (int i = threadIdx.x; i < nbt; i += 1024)
        cnt_sb[(t * STRIPES + s) * nbt + i] = min(cur[i], RCAP);
}

// Pass B: one WG per (type,bucket). Consume loop flattened over
// (stripe x slot) so all 256 lanes stay active. Place records at final
// padded positions via LDS per-row cursors, write the span densely.
__global__ __launch_bounds__(256) void place_pass(const int2* __restrict__ rbuf,
                                                  const int* __restrict__ cnt_sb,
                                                  const int* __restrict__ start,
                                                  int2* __restrict__ spair,
                                                  int N, int nbt) {
    __shared__ int  lcur[BROWS];
    __shared__ int  scnt[STRIPES];
    __shared__ int2 span[SPANCAP];
    const int b = blockIdx.x;
    const int t = blockIdx.y;
    const int r0 = b * BROWS;
    const int rows_here = min(BROWS, N - r0);
    if (rows_here <= 0) return;
    const int g0 = t * N + r0;
    const int p0 = start[g0];
    const int p1 = start[g0 + rows_here];
    const int spanlen = p1 - p0;        // <= SPANCAP by construction

    for (int i = threadIdx.x; i < spanlen; i += 256) span[i] = make_int2(0, 0);
    for (int i = threadIdx.x; i < rows_here; i += 256) lcur[i] = start[g0 + i] - p0;
    for (int i = threadIdx.x; i < STRIPES; i += 256)
        scnt[i] = cnt_sb[(t * STRIPES + i) * nbt + b];
    __syncthreads();

    const size_t tb = (size_t)t * STRIPES;
    for (int idx = threadIdx.x; idx < STRIPES * RCAP; idx += 256) {
        int s = idx / RCAP;
        int i = idx - s * RCAP;
        if (i < scnt[s]) {
            int2 q = rbuf[((tb + s) * nbt + b) * RCAP + i];
            int rl = ((unsigned)q.x) >> 17;
            int pos = atomicAdd(&lcur[rl], 1);
            if (pos < SPANCAP) span[pos] = make_int2(q.x & 0x1FFFF, q.y);
        }
    }
    __syncthreads();
    int2* out = spair + p0;
    for (int i = threadIdx.x; i < spanlen; i += 256) out[i] = span[i];
}

// --- gathers (fp16 tables) -------------------------------------------------

// layer 1 (gather-after): h1_h[row] = sum_{t=2h,2h+1} adj_t-row . hw16_t
__global__ __launch_bounds__(256) void gatherA(const __half* __restrict__ hw16,
                                               const int* __restrict__ start,
                                               const int4* __restrict__ sp4,
                                               float* __restrict__ h32,
                                               __half* __restrict__ h16, int N) {
    const int half = blockIdx.y;
    const int row  = blockIdx.x * 4 + (threadIdx.x >> 6);
    const int lane = threadIdx.x & 63;
    if (row >= N) return;
    const size_t NH = (size_t)N * HDIM;
    float accA = 0.f, accB = 0.f;

#pragma unroll
    for (int p = 0; p < 2; p++) {
        const int tt = half * 2 + p;
        const __half* __restrict__ h = hw16 + (size_t)tt * NH;
        int beg = __builtin_amdgcn_readfirstlane(start[tt * N + row]);
        int end = __builtin_amdgcn_readfirstlane(start[tt * N + row + 1]);
        for (int e = beg; e < end; e += 8) {
            int c[8]; float v[8];
#pragma unroll
            for (int u = 0; u < 4; u++) {
                int4 q = sp4[(e >> 1) + u];
                c[2 * u]     = q.x; v[2 * u]     = __int_as_float(q.y);
                c[2 * u + 1] = q.z; v[2 * u + 1] = __int_as_float(q.w);
            }
            float hv[8];
#pragma unroll
            for (int u = 0; u < 8; u++)
                hv[u] = __half2float(h[(size_t)c[u] * HDIM + lane]);
#pragma unroll
            for (int u = 0; u < 8; u += 2) {
                accA = fmaf(v[u],     hv[u],     accA);
                accB = fmaf(v[u + 1], hv[u + 1], accB);
            }
        }
    }
    float r = accA + accB;
    size_t idx = (size_t)half * NH + (size_t)row * HDIM + lane;
    h32[idx] = r;
    h16[idx] = __float2half_rn(r);
}

// layers 2-5 (gather-first): g_h[row][p*64+lane] = adj_{2h+p}-row . relu(in16_{p})
__global__ __launch_bounds__(256) void gatherF(const __half* __restrict__ in16,
                                               const int* __restrict__ start,
                                               const int4* __restrict__ sp4,
                                               float* __restrict__ g, int N) {
    const int half = blockIdx.y;
    const int row  = blockIdx.x * 4 + (threadIdx.x >> 6);
    const int lane = threadIdx.x & 63;
    if (row >= N) return;
    const size_t NH = (size_t)N * HDIM;
    float* gout = g + ((size_t)half * N + row) * 128 + lane;

#pragma unroll
    for (int p = 0; p < 2; p++) {
        const int tt = half * 2 + p;
        const __half* __restrict__ h = in16 + (size_t)(tt & 1) * NH;
        int beg = __builtin_amdgcn_readfirstlane(start[tt * N + row]);
        int end = __builtin_amdgcn_readfirstlane(start[tt * N + row + 1]);
        float accA = 0.f, accB = 0.f;
        for (int e = beg; e < end; e += 8) {
            int c[8]; float v[8];
#pragma unroll
            for (int u = 0; u < 4; u++) {
                int4 q = sp4[(e >> 1) + u];
                c[2 * u]     = q.x; v[2 * u]     = __int_as_float(q.y);
                c[2 * u + 1] = q.z; v[2 * u + 1] = __int_as_float(q.w);
            }
            float hv[8];
#pragma unroll
            for (int u = 0; u < 8; u++)
                hv[u] = fmaxf(__half2float(h[(size_t)c[u] * HDIM + lane]), 0.f);
#pragma unroll
            for (int u = 0; u < 8; u += 2) {
                accA = fmaf(v[u],     hv[u],     accA);
                accB = fmaf(v[u + 1], hv[u + 1], accB);
            }
        }
        gout[p * 64] = accA + accB;
    }
}

extern "C" void kernel_launch(void* const* d_in, const int* in_sizes, int n_in,
                              void* d_out, int out_size, void* d_ws, size_t ws_size,
                              hipStream_t stream) {
    const float* feat0 = (const float*)d_in[0];
    const float* feat1 = (const float*)d_in[1];
    const int*   rows  = (const int*)d_in[2];
    const int*   cols  = (const int*)d_in[3];
    const float* vals  = (const float*)d_in[4];
    const float* W1    = (const float*)d_in[5];
    const float* W2    = (const float*)d_in[6];
    const float* W3    = (const float*)d_in[7];
    const float* W4    = (const float*)d_in[8];
    const float* W5    = (const float*)d_in[9];
    const float* att   = (const float*)d_in[10];

    const int N = in_sizes[0] / 128;   // 100000
    const int E = in_sizes[2] / 4;     // 1000000
    const size_t NH = (size_t)N * HDIM;
    const int M = 4 * N;
    const int PadCap = 4 * E + 7 * M;  // max padded CSR entries
    const int nbt = (N + BROWS - 1) / BROWS;   // buckets per type (782)

    float* ws  = (float*)d_ws;
    float* h10 = ws + 0 * NH;            // h1 fp32 [2NH] (epilogue residual)
    float* e10 = ws + 2 * NH;            // e1 fp32 [2NH] (epilogue)
    float* g   = ws + 4 * NH;            // [2][N][128] fp32; aliases hw16 + rbuf
    __half* hw16 = (__half*)g;           // [4][N][64] fp16 (layer-1 only)
    int2*   rbuf = (int2*)g;             // 256*nbt*RCAP records (96.1MB, build only)
    __half* f16  = (__half*)(ws + 8 * NH);
    __half* h16  = f16 + 0 * 2 * NH;     // [2][N][64] fp16 each
    __half* e16  = f16 + 1 * 2 * NH;
    __half* a16  = f16 + 2 * 2 * NH;
    __half* b16  = f16 + 3 * 2 * NH;     // f16 region = 8NH halves = 4NH floats

    int2*  spair    = (int2*)(ws + 12 * NH);       // PadCap pairs (16B-aligned)
    int*   start    = (int*)(spair + PadCap);      // M+1
    int*   cursor   = start + (M + 1);             // M (hist counts)
    int*   partials = cursor + M;                  // <=1024
    int*   cnt_sb   = partials + 1024;             // 256*nbt

    const int gblk = (N + 63) / 64;
    const int eblk = (E + 255) / 256;
    const int B    = (M + 1023) / 1024;
    const int gr2  = (N + 3) / 4;

    // ---- CSR build (once; graph reused by all 5 layers) ----
    hipMemsetAsync(cursor, 0, (size_t)M * sizeof(int), stream);
    hist4<<<dim3(eblk, 4), 256, 0, stream>>>(rows, cursor, E, N);
    scan_sums<<<B, 256, 0, stream>>>(cursor, partials, M);
    scan_partials<<<1, 1024, 0, stream>>>(partials, B);
    scan_final<<<B, 256, 0, stream>>>(cursor, partials, start, M);
    split_pass<<<dim3(STRIPES, 4), 1024, 0, stream>>>(rows, cols, vals, rbuf, cnt_sb, E, nbt);
    place_pass<<<dim3(nbt, 4), 256, 0, stream>>>(rbuf, cnt_sb, start, spair, N, nbt);

    const int4* sp4 = (const int4*)spair;

    // ---- layer 1: GEMM-first (feat is 128-wide), gather-after ----
    gemm_l1<<<dim3(gblk, 4), 256, 0, stream>>>(feat0, feat1, W1, hw16, N);
    gatherA<<<dim3(gr2, 2), 256, 0, stream>>>(hw16, start, sp4, h10, h16, N);

    // ---- layer 2: gather-first, GEMM stores fp32+fp16 (e1 feeds epilogue) ----
    gatherF<<<dim3(gr2, 2), 256, 0, stream>>>(h16, start, sp4, g, N);
    gemm_h2<1><<<dim3(gblk, 2), 256, 0, stream>>>(g, W2, e16, e10,
                                                  nullptr, nullptr, nullptr, nullptr, N);

    // ---- layers 3-4: gather-first, fp16-only pre-act ----
    gatherF<<<dim3(gr2, 2), 256, 0, stream>>>(e16, start, sp4, g, N);
    gemm_h2<0><<<dim3(gblk, 2), 256, 0, stream>>>(g, W3, a16, nullptr,
                                                  nullptr, nullptr, nullptr, nullptr, N);
    gatherF<<<dim3(gr2, 2), 256, 0, stream>>>(a16, start, sp4, g, N);
    gemm_h2<0><<<dim3(gblk, 2), 256, 0, stream>>>(g, W4, b16, nullptr,
                                                  nullptr, nullptr, nullptr, nullptr, N);

    // ---- layer 5: gather-first + GEMM with fused attention/concat epilogue ----
    gatherF<<<dim3(gr2, 2), 256, 0, stream>>>(b16, start, sp4, g, N);
    gemm_h2<2><<<dim3(gblk, 2), 256, 0, stream>>>(g, W5, nullptr, nullptr,
                                                  h10, e10, att, (float*)d_out, N);
}

// Round 9
// 1220.102 us; speedup vs baseline: 1.7127x; 1.1283x over previous
//
#include <hip/hip_runtime.h>
#include <hip/hip_fp16.h>

// ---------------------------------------------------------------------------
// Decagon GCN forward, round 10 (resubmit — R10 bench was an infra failure:
// "container failed twice", no pytest/rocprof; source re-audited, no defect
// found, resubmitting unchanged to preserve the A/B vs R9, same as the R5
// resubmit precedent).
// R9 post-mortem: split/place fixed; hist4 became top kernel (155us,
// WRITE 124MB for a 1.6MB histogram): 4M device-scope atomicAdds make cnt
// lines ping-pong across the 8 non-coherent XCD L2s (every migration = TCC
// writeback+fetch). Third presentation of the same disease.
// R10: histogram derived from split records — zero global atomics in the
// whole CSR build:
//   order: split_pass -> count_pass -> scans -> place_pass
//   count_pass: one WG per (type,bucket); dense read of its 64 stripe
//     regions, per-row LDS counters, dense 128-int write to cnt.
//   hist4 + cursor memset deleted.
// Everything else identical to R9 (fp16 gather tables, fused GEMMs).
// ---------------------------------------------------------------------------

#define HDIM 64
#define STRIPES 64     // edge stripes per type
#define BROWS   128    // rows per bucket
#define RCAP    60     // records per (stripe,bucket); mean 20 + 8.9 sigma
#define SPANCAP 3072   // LDS span entries per bucket; max ~2500

__device__ inline unsigned pack2h(float a, float b) {
    return (unsigned)__half_as_ushort(__float2half_rn(a)) |
           ((unsigned)__half_as_ushort(__float2half_rn(b)) << 16);
}

// ---- layer-1 GEMM: hw16_t[N,64] = feat_{t&1}[N,128] @ W1_t[128,64], t=blockIdx.y
__global__ __launch_bounds__(256) void gemm_l1(const float* __restrict__ in0,
                                               const float* __restrict__ in1,
                                               const float* __restrict__ Wall,
                                               __half* __restrict__ hw16, int N) {
    const int K = 128;
    __shared__ __align__(16) float Ws[128 * 64];
    __shared__ __align__(16) float As[16 * 68];

    const int t = blockIdx.y;
    const float* A = (t & 1) ? in1 : in0;
    const float* W = Wall + (size_t)t * K * HDIM;
    __half*      C = hw16 + (size_t)t * (size_t)N * HDIM;

    const int tid  = threadIdx.x;
    const int row0 = blockIdx.x * 64;

    for (int off = tid * 4; off < K * 64; off += 1024)
        *(float4*)(Ws + off) = *(const float4*)(W + off);

    const int tx = tid & 15;
    const int ty = tid >> 4;
    const int lr = tid >> 2;
    const int kq = tid & 3;

    float acc[4][4];
#pragma unroll
    for (int i = 0; i < 4; i++)
#pragma unroll
        for (int j = 0; j < 4; j++) acc[i][j] = 0.f;

    const int grow = row0 + lr;
    const float* Arow = A + (size_t)grow * K;

    for (int k0 = 0; k0 < K; k0 += 16) {
        __syncthreads();
        float4 av = make_float4(0.f, 0.f, 0.f, 0.f);
        if (grow < N) av = *(const float4*)(Arow + k0 + kq * 4);
        As[(kq * 4 + 0) * 68 + lr] = av.x;
        As[(kq * 4 + 1) * 68 + lr] = av.y;
        As[(kq * 4 + 2) * 68 + lr] = av.z;
        As[(kq * 4 + 3) * 68 + lr] = av.w;
        __syncthreads();

#pragma unroll
        for (int kk = 0; kk < 16; kk++) {
            float4 a4 = *(const float4*)(As + kk * 68 + ty * 4);
            float4 b4 = *(const float4*)(Ws + (k0 + kk) * 64 + tx * 4);
            float avv[4] = {a4.x, a4.y, a4.z, a4.w};
            float bvv[4] = {b4.x, b4.y, b4.z, b4.w};
#pragma unroll
            for (int i = 0; i < 4; i++)
#pragma unroll
                for (int j = 0; j < 4; j++)
                    acc[i][j] = fmaf(avv[i], bvv[j], acc[i][j]);
        }
    }

#pragma unroll
    for (int i = 0; i < 4; i++) {
        int r = row0 + ty * 4 + i;
        if (r < N) {
            uint2 pk;
            pk.x = pack2h(acc[i][0], acc[i][1]);
            pk.y = pack2h(acc[i][2], acc[i][3]);
            *(uint2*)(C + (size_t)r * HDIM + tx * 4) = pk;
        }
    }
}

// ---- layers 2-5 GEMM: C_h[N,64] = g_h[N,128] @ Wstack_h[128,64], h=blockIdx.y
// MODE 0: fp16 pre-act only (e2,e3).  MODE 1: fp16 + fp32 pre-act (e1).
// MODE 2: FIN epilogue  out = concat(relu(h1)*a0, relu(e1)*a1, (p+relu(h1))*a2)
template <int MODE>
__global__ __launch_bounds__(256) void gemm_h2(const float* __restrict__ g,
                                               const float* __restrict__ Wl,
                                               __half* __restrict__ o16,
                                               float* __restrict__ o32,
                                               const float* __restrict__ h1,
                                               const float* __restrict__ e1,
                                               const float* __restrict__ att,
                                               float* __restrict__ outF, int N) {
    const int K = 128;
    __shared__ __align__(16) float Ws[128 * 64];
    __shared__ __align__(16) float As[16 * 68];

    const int t = blockIdx.y;
    const size_t NH = (size_t)N * HDIM;
    const float* A = g + (size_t)t * (size_t)N * K;
    const float* W = Wl + (size_t)t * 8192;   // [W_{2t}; W_{2t+1}] contiguous

    const int tid  = threadIdx.x;
    const int row0 = blockIdx.x * 64;

    for (int off = tid * 4; off < K * 64; off += 1024)
        *(float4*)(Ws + off) = *(const float4*)(W + off);

    const int tx = tid & 15;
    const int ty = tid >> 4;
    const int lr = tid >> 2;
    const int kq = tid & 3;

    float acc[4][4];
#pragma unroll
    for (int i = 0; i < 4; i++)
#pragma unroll
        for (int j = 0; j < 4; j++) acc[i][j] = 0.f;

    const int grow = row0 + lr;
    const float* Arow = A + (size_t)grow * K;

    for (int k0 = 0; k0 < K; k0 += 16) {
        __syncthreads();
        float4 av = make_float4(0.f, 0.f, 0.f, 0.f);
        if (grow < N) av = *(const float4*)(Arow + k0 + kq * 4);
        As[(kq * 4 + 0) * 68 + lr] = av.x;
        As[(kq * 4 + 1) * 68 + lr] = av.y;
        As[(kq * 4 + 2) * 68 + lr] = av.z;
        As[(kq * 4 + 3) * 68 + lr] = av.w;
        __syncthreads();

#pragma unroll
        for (int kk = 0; kk < 16; kk++) {
            float4 a4 = *(const float4*)(As + kk * 68 + ty * 4);
            float4 b4 = *(const float4*)(Ws + (k0 + kk) * 64 + tx * 4);
            float avv[4] = {a4.x, a4.y, a4.z, a4.w};
            float bvv[4] = {b4.x, b4.y, b4.z, b4.w};
#pragma unroll
            for (int i = 0; i < 4; i++)
#pragma unroll
                for (int j = 0; j < 4; j++)
                    acc[i][j] = fmaf(avv[i], bvv[j], acc[i][j]);
        }
    }

    if (MODE != 2) {
#pragma unroll
        for (int i = 0; i < 4; i++) {
            int r = row0 + ty * 4 + i;
            if (r < N) {
                size_t idx = (size_t)t * NH + (size_t)r * HDIM + tx * 4;
                uint2 pk;
                pk.x = pack2h(acc[i][0], acc[i][1]);
                pk.y = pack2h(acc[i][2], acc[i][3]);
                *(uint2*)(o16 + idx) = pk;
                if (MODE == 1) {
                    float4 o = make_float4(acc[i][0], acc[i][1], acc[i][2], acc[i][3]);
                    *(float4*)(o32 + idx) = o;
                }
            }
        }
    } else {
        const float a0 = att[0], a1 = att[1], a2 = att[2];
#pragma unroll
        for (int i = 0; i < 4; i++) {
            int r = row0 + ty * 4 + i;
            if (r < N) {
                size_t idx = (size_t)t * NH + (size_t)r * HDIM + tx * 4;
                float4 h4 = *(const float4*)(h1 + idx);
                float4 e4 = *(const float4*)(e1 + idx);
                float hh[4] = {fmaxf(h4.x, 0.f), fmaxf(h4.y, 0.f),
                               fmaxf(h4.z, 0.f), fmaxf(h4.w, 0.f)};
                float ee[4] = {fmaxf(e4.x, 0.f), fmaxf(e4.y, 0.f),
                               fmaxf(e4.z, 0.f), fmaxf(e4.w, 0.f)};
                size_t base = (size_t)t * (size_t)N * 192 + (size_t)r * 192 + tx * 4;
                *(float4*)(outF + base) =
                    make_float4(hh[0] * a0, hh[1] * a0, hh[2] * a0, hh[3] * a0);
                *(float4*)(outF + base + 64) =
                    make_float4(ee[0] * a1, ee[1] * a1, ee[2] * a1, ee[3] * a1);
                *(float4*)(outF + base + 128) =
                    make_float4((acc[i][0] + hh[0]) * a2, (acc[i][1] + hh[1]) * a2,
                                (acc[i][2] + hh[2]) * a2, (acc[i][3] + hh[3]) * a2);
            }
        }
    }
}

// --- CSR build (no global atomics anywhere) --------------------------------

// Pass A: stripe (blockIdx.x, 64) x type (blockIdx.y, 4) = 256 WGs x 1024 thr.
// Append (row_local||col, val) into PRIVATE per-(stripe,bucket) regions via
// LDS cursors. Hot tail lines ~50KB/WG, 32 WGs/XCD -> single-XCD L2 ->
// dense writebacks.
__global__ __launch_bounds__(1024) void split_pass(const int* __restrict__ rows,
                                                   const int* __restrict__ cols,
                                                   const float* __restrict__ vals,
                                                   int2* __restrict__ rbuf,
                                                   int* __restrict__ cnt_sb,
                                                   int E, int nbt) {
    __shared__ int cur[1024];           // nbt <= 1024
    const int s = blockIdx.x;
    const int t = blockIdx.y;
    for (int i = threadIdx.x; i < nbt; i += 1024) cur[i] = 0;
    __syncthreads();

    const int es = (E + STRIPES - 1) / STRIPES;
    const int e0 = s * es;
    const int e1 = min(e0 + es, E);
    const size_t base = (size_t)t * E;
    int2* rb = rbuf + (size_t)(t * STRIPES + s) * nbt * RCAP;

    for (int e = e0 + threadIdx.x; e < e1; e += 1024) {
        int r = rows[base + e];
        int b = r >> 7;                 // BROWS = 128
        int idx = atomicAdd(&cur[b], 1);
        if (idx < RCAP) {               // ~9-sigma margin; guard vs OOB
            int rl = r & 127;
            rb[(size_t)b * RCAP + idx] =
                make_int2((rl << 17) | cols[base + e], __float_as_int(vals[base + e]));
        }
    }
    __syncthreads();
    for (int i = threadIdx.x; i < nbt; i += 1024)
        cnt_sb[(t * STRIPES + s) * nbt + i] = min(cur[i], RCAP);
}

// Histogram from records: one WG per (type,bucket). Dense reads of the 64
// stripe regions, per-row LDS counters, dense 128-int write to cnt.
__global__ __launch_bounds__(256) void count_pass(const int2* __restrict__ rbuf,
                                                  const int* __restrict__ cnt_sb,
                                                  int* __restrict__ cnt,
                                                  int N, int nbt) {
    __shared__ int lcnt[BROWS];
    __shared__ int scnt[STRIPES];
    const int b = blockIdx.x;
    const int t = blockIdx.y;
    const int r0 = b * BROWS;
    const int rows_here = min(BROWS, N - r0);
    if (rows_here <= 0) return;

    for (int i = threadIdx.x; i < BROWS; i += 256) lcnt[i] = 0;
    for (int i = threadIdx.x; i < STRIPES; i += 256)
        scnt[i] = cnt_sb[(t * STRIPES + i) * nbt + b];
    __syncthreads();

    const size_t tb = (size_t)t * STRIPES;
    for (int idx = threadIdx.x; idx < STRIPES * RCAP; idx += 256) {
        int s = idx / RCAP;
        int i = idx - s * RCAP;
        if (i < scnt[s]) {
            int2 q = rbuf[((tb + s) * nbt + b) * RCAP + i];
            atomicAdd(&lcnt[((unsigned)q.x) >> 17], 1);
        }
    }
    __syncthreads();
    for (int i = threadIdx.x; i < rows_here; i += 256)
        cnt[t * N + r0 + i] = lcnt[i];
}

__global__ __launch_bounds__(256) void scan_sums(const int* __restrict__ cnt,
                                                 int* __restrict__ partials, int M) {
    __shared__ int red[256];
    int base = blockIdx.x * 1024 + threadIdx.x * 4;
    int s = 0;
#pragma unroll
    for (int j = 0; j < 4; j++) {
        int i = base + j;
        if (i < M) s += (cnt[i] + 7) & ~7;
    }
    red[threadIdx.x] = s;
    __syncthreads();
    for (int off = 128; off > 0; off >>= 1) {
        if (threadIdx.x < off) red[threadIdx.x] += red[threadIdx.x + off];
        __syncthreads();
    }
    if (threadIdx.x == 0) partials[blockIdx.x] = red[0];
}

__global__ __launch_bounds__(1024) void scan_partials(int* __restrict__ partials, int B) {
    __shared__ int buf[1024];
    int t = threadIdx.x;
    int v = (t < B) ? partials[t] : 0;
    buf[t] = v;
    __syncthreads();
    for (int off = 1; off < 1024; off <<= 1) {
        int add = (t >= off) ? buf[t - off] : 0;
        __syncthreads();
        buf[t] += add;
        __syncthreads();
    }
    if (t < B) partials[t] = buf[t] - v;  // exclusive
}

__global__ __launch_bounds__(256) void scan_final(int* __restrict__ cnt,
                                                  const int* __restrict__ partials,
                                                  int* __restrict__ start, int M) {
    __shared__ int red[256];
    int tid = threadIdx.x;
    int base = blockIdx.x * 1024 + tid * 4;
    int v[4];
    int s = 0;
#pragma unroll
    for (int j = 0; j < 4; j++) {
        int i = base + j;
        v[j] = (i < M) ? ((cnt[i] + 7) & ~7) : 0;
        s += v[j];
    }
    red[tid] = s;
    __syncthreads();
    int mine = s;
    for (int off = 1; off < 256; off <<= 1) {
        int add = (tid >= off) ? red[tid - off] : 0;
        __syncthreads();
        red[tid] += add;
        __syncthreads();
    }
    int excl = red[tid] - mine + partials[blockIdx.x];
#pragma unroll
    for (int j = 0; j < 4; j++) {
        int i = base + j;
        if (i < M) {
            start[i] = excl;
            excl += v[j];
            if (i == M - 1) start[M] = excl;
        }
    }
}

// Pass B: one WG per (type,bucket). Consume loop flattened over
// (stripe x slot) so all 256 lanes stay active. Place records at final
// padded positions via LDS per-row cursors, write the span densely.
__global__ __launch_bounds__(256) void place_pass(const int2* __restrict__ rbuf,
                                                  const int* __restrict__ cnt_sb,
                                                  const int* __restrict__ start,
                                                  int2* __restrict__ spair,
                                                  int N, int nbt) {
    __shared__ int  lcur[BROWS];
    __shared__ int  scnt[STRIPES];
    __shared__ int2 span[SPANCAP];
    const int b = blockIdx.x;
    const int t = blockIdx.y;
    const int r0 = b * BROWS;
    const int rows_here = min(BROWS, N - r0);
    if (rows_here <= 0) return;
    const int g0 = t * N + r0;
    const int p0 = start[g0];
    const int p1 = start[g0 + rows_here];
    const int spanlen = p1 - p0;        // <= SPANCAP by construction

    for (int i = threadIdx.x; i < spanlen; i += 256) span[i] = make_int2(0, 0);
    for (int i = threadIdx.x; i < rows_here; i += 256) lcur[i] = start[g0 + i] - p0;
    for (int i = threadIdx.x; i < STRIPES; i += 256)
        scnt[i] = cnt_sb[(t * STRIPES + i) * nbt + b];
    __syncthreads();

    const size_t tb = (size_t)t * STRIPES;
    for (int idx = threadIdx.x; idx < STRIPES * RCAP; idx += 256) {
        int s = idx / RCAP;
        int i = idx - s * RCAP;
        if (i < scnt[s]) {
            int2 q = rbuf[((tb + s) * nbt + b) * RCAP + i];
            int rl = ((unsigned)q.x) >> 17;
            int pos = atomicAdd(&lcur[rl], 1);
            if (pos < SPANCAP) span[pos] = make_int2(q.x & 0x1FFFF, q.y);
        }
    }
    __syncthreads();
    int2* out = spair + p0;
    for (int i = threadIdx.x; i < spanlen; i += 256) out[i] = span[i];
}

// --- gathers (fp16 tables) -------------------------------------------------

// layer 1 (gather-after): h1_h[row] = sum_{t=2h,2h+1} adj_t-row . hw16_t
__global__ __launch_bounds__(256) void gatherA(const __half* __restrict__ hw16,
                                               const int* __restrict__ start,
                                               const int4* __restrict__ sp4,
                                               float* __restrict__ h32,
                                               __half* __restrict__ h16, int N) {
    const int half = blockIdx.y;
    const int row  = blockIdx.x * 4 + (threadIdx.x >> 6);
    const int lane = threadIdx.x & 63;
    if (row >= N) return;
    const size_t NH = (size_t)N * HDIM;
    float accA = 0.f, accB = 0.f;

#pragma unroll
    for (int p = 0; p < 2; p++) {
        const int tt = half * 2 + p;
        const __half* __restrict__ h = hw16 + (size_t)tt * NH;
        int beg = __builtin_amdgcn_readfirstlane(start[tt * N + row]);
        int end = __builtin_amdgcn_readfirstlane(start[tt * N + row + 1]);
        for (int e = beg; e < end; e += 8) {
            int c[8]; float v[8];
#pragma unroll
            for (int u = 0; u < 4; u++) {
                int4 q = sp4[(e >> 1) + u];
                c[2 * u]     = q.x; v[2 * u]     = __int_as_float(q.y);
                c[2 * u + 1] = q.z; v[2 * u + 1] = __int_as_float(q.w);
            }
            float hv[8];
#pragma unroll
            for (int u = 0; u < 8; u++)
                hv[u] = __half2float(h[(size_t)c[u] * HDIM + lane]);
#pragma unroll
            for (int u = 0; u < 8; u += 2) {
                accA = fmaf(v[u],     hv[u],     accA);
                accB = fmaf(v[u + 1], hv[u + 1], accB);
            }
        }
    }
    float r = accA + accB;
    size_t idx = (size_t)half * NH + (size_t)row * HDIM + lane;
    h32[idx] = r;
    h16[idx] = __float2half_rn(r);
}

// layers 2-5 (gather-first): g_h[row][p*64+lane] = adj_{2h+p}-row . relu(in16_{p})
__global__ __launch_bounds__(256) void gatherF(const __half* __restrict__ in16,
                                               const int* __restrict__ start,
                                               const int4* __restrict__ sp4,
                                               float* __restrict__ g, int N) {
    const int half = blockIdx.y;
    const int row  = blockIdx.x * 4 + (threadIdx.x >> 6);
    const int lane = threadIdx.x & 63;
    if (row >= N) return;
    const size_t NH = (size_t)N * HDIM;
    float* gout = g + ((size_t)half * N + row) * 128 + lane;

#pragma unroll
    for (int p = 0; p < 2; p++) {
        const int tt = half * 2 + p;
        const __half* __restrict__ h = in16 + (size_t)(tt & 1) * NH;
        int beg = __builtin_amdgcn_readfirstlane(start[tt * N + row]);
        int end = __builtin_amdgcn_readfirstlane(start[tt * N + row + 1]);
        float accA = 0.f, accB = 0.f;
        for (int e = beg; e < end; e += 8) {
            int c[8]; float v[8];
#pragma unroll
            for (int u = 0; u < 4; u++) {
                int4 q = sp4[(e >> 1) + u];
                c[2 * u]     = q.x; v[2 * u]     = __int_as_float(q.y);
                c[2 * u + 1] = q.z; v[2 * u + 1] = __int_as_float(q.w);
            }
            float hv[8];
#pragma unroll
            for (int u = 0; u < 8; u++)
                hv[u] = fmaxf(__half2float(h[(size_t)c[u] * HDIM + lane]), 0.f);
#pragma unroll
            for (int u = 0; u < 8; u += 2) {
                accA = fmaf(v[u],     hv[u],     accA);
                accB = fmaf(v[u + 1], hv[u + 1], accB);
            }
        }
        gout[p * 64] = accA + accB;
    }
}

extern "C" void kernel_launch(void* const* d_in, const int* in_sizes, int n_in,
                              void* d_out, int out_size, void* d_ws, size_t ws_size,
                              hipStream_t stream) {
    const float* feat0 = (const float*)d_in[0];
    const float* feat1 = (const float*)d_in[1];
    const int*   rows  = (const int*)d_in[2];
    const int*   cols  = (const int*)d_in[3];
    const float* vals  = (const float*)d_in[4];
    const float* W1    = (const float*)d_in[5];
    const float* W2    = (const float*)d_in[6];
    const float* W3    = (const float*)d_in[7];
    const float* W4    = (const float*)d_in[8];
    const float* W5    = (const float*)d_in[9];
    const float* att   = (const float*)d_in[10];

    const int N = in_sizes[0] / 128;   // 100000
    const int E = in_sizes[2] / 4;     // 1000000
    const size_t NH = (size_t)N * HDIM;
    const int M = 4 * N;
    const int PadCap = 4 * E + 7 * M;  // max padded CSR entries
    const int nbt = (N + BROWS - 1) / BROWS;   // buckets per type (782)

    float* ws  = (float*)d_ws;
    float* h10 = ws + 0 * NH;            // h1 fp32 [2NH] (epilogue residual)
    float* e10 = ws + 2 * NH;            // e1 fp32 [2NH] (epilogue)
    float* g   = ws + 4 * NH;            // [2][N][128] fp32; aliases hw16 + rbuf
    __half* hw16 = (__half*)g;           // [4][N][64] fp16 (layer-1 only)
    int2*   rbuf = (int2*)g;             // 256*nbt*RCAP records (96.1MB, build only)
    __half* f16  = (__half*)(ws + 8 * NH);
    __half* h16  = f16 + 0 * 2 * NH;     // [2][N][64] fp16 each
    __half* e16  = f16 + 1 * 2 * NH;
    __half* a16  = f16 + 2 * 2 * NH;
    __half* b16  = f16 + 3 * 2 * NH;     // f16 region = 8NH halves = 4NH floats

    int2*  spair    = (int2*)(ws + 12 * NH);       // PadCap pairs (16B-aligned)
    int*   start    = (int*)(spair + PadCap);      // M+1
    int*   cnt      = start + (M + 1);             // M (raw counts)
    int*   partials = cnt + M;                     // <=1024
    int*   cnt_sb   = partials + 1024;             // 256*nbt

    const int gblk = (N + 63) / 64;
    const int B    = (M + 1023) / 1024;
    const int gr2  = (N + 3) / 4;

    // ---- CSR build (once; graph reused by all 5 layers; NO global atomics) ----
    split_pass<<<dim3(STRIPES, 4), 1024, 0, stream>>>(rows, cols, vals, rbuf, cnt_sb, E, nbt);
    count_pass<<<dim3(nbt, 4), 256, 0, stream>>>(rbuf, cnt_sb, cnt, N, nbt);
    scan_sums<<<B, 256, 0, stream>>>(cnt, partials, M);
    scan_partials<<<1, 1024, 0, stream>>>(partials, B);
    scan_final<<<B, 256, 0, stream>>>(cnt, partials, start, M);
    place_pass<<<dim3(nbt, 4), 256, 0, stream>>>(rbuf, cnt_sb, start, spair, N, nbt);

    const int4* sp4 = (const int4*)spair;

    // ---- layer 1: GEMM-first (feat is 128-wide), gather-after ----
    gemm_l1<<<dim3(gblk, 4), 256, 0, stream>>>(feat0, feat1, W1, hw16, N);
    gatherA<<<dim3(gr2, 2), 256, 0, stream>>>(hw16, start, sp4, h10, h16, N);

    // ---- layer 2: gather-first, GEMM stores fp32+fp16 (e1 feeds epilogue) ----
    gatherF<<<dim3(gr2, 2), 256, 0, stream>>>(h16, start, sp4, g, N);
    gemm_h2<1><<<dim3(gblk, 2), 256, 0, stream>>>(g, W2, e16, e10,
                                                  nullptr, nullptr, nullptr, nullptr, N);

    // ---- layers 3-4: gather-first, fp16-only pre-act ----
    gatherF<<<dim3(gr2, 2), 256, 0, stream>>>(e16, start, sp4, g, N);
    gemm_h2<0><<<dim3(gblk, 2), 256, 0, stream>>>(g, W3, a16, nullptr,
                                                  nullptr, nullptr, nullptr, nullptr, N);
    gatherF<<<dim3(gr2, 2), 256, 0, stream>>>(a16, start, sp4, g, N);
    gemm_h2<0><<<dim3(gblk, 2), 256, 0, stream>>>(g, W4, b16, nullptr,
                                                  nullptr, nullptr, nullptr, nullptr, N);

    // ---- layer 5: gather-first + GEMM with fused attention/concat epilogue ----
    gatherF<<<dim3(gr2, 2), 256, 0, stream>>>(b16, start, sp4, g, N);
    gemm_h2<2><<<dim3(gblk, 2), 256, 0, stream>>>(g, W5, nullptr, nullptr,
                                                  h10, e10, att, (float*)d_out, N);
}